// Round 3
// baseline (46.387 us; speedup 1.0000x reference)
//
#include <hip/hip_runtime.h>

// Conv2d 16->16, k=3, stride 1, pad 1, H=W=1024.
// Round 4: counted-vmcnt pipeline (T3/T4), raw s_barrier, LDS double-buffer.
//   Rounds 1-3 post-mortem: all stuck at 41-44us (~45% HBM duty) because
//   __syncthreads() emits s_waitcnt vmcnt(0) before s_barrier -- every
//   prefetch was drained at the next barrier (guide §5: the m97 structural
//   stall). Fix: inline-asm s_barrier + lgkmcnt(0) only; global loads for
//   tile t+1 stay in flight across the barrier and under compute(t). The
//   compiler then emits a *counted* vmcnt wait at pack(t)'s first use.
//   Per block: NT=4 stacked tiles, LDS double-buffered (42 KB, ONE barrier
//   per tile: buf[t&1] readers are compute(t-2), all complete before
//   barrier(t-1) which precedes pack(t)). Load regs double-buffered
//   L[2][16] (static idx after unroll). launch_bounds(256,2) -> VGPR cap
//   256 so 2x16 dwordx4 really stay live. Grid 512 = 2 blocks/CU.
//   GEMM view per tile unchanged: D[px][co] = sum_k B[px][k]*A[k][co],
//   K=160 = 5 x mfma_f32_16x16x32_bf16; LDS [y][x][ci] bf16 with 2-bit
//   XOR swizzle on bits 4-5; weights pre-shuffled by prep kernel.

#define H 1024
#define W 1024
#define HW (H * W)
#define TW 64
#define TH 8
#define NT 4                 // tiles per block, stacked vertically
#define LROWS 10             // TH + 2 halo rows
#define LPITCH 2112          // 66 cols * 32 B (16 ci * 2 B)
#define LDS_TILE (LROWS * LPITCH)    // 21120
#define LDS_BYTES (2 * LDS_TILE)     // 42240 (double buffer)

typedef __bf16 bf16x8 __attribute__((ext_vector_type(8)));
typedef float f32x4 __attribute__((ext_vector_type(4)));
typedef unsigned short ushort8 __attribute__((ext_vector_type(8)));
typedef unsigned int uint4v __attribute__((ext_vector_type(4)));

__device__ __host__ inline unsigned short f2bf(float f) {
  unsigned u = __builtin_bit_cast(unsigned, f);
  return (unsigned short)((u + 0x7fffu + ((u >> 16) & 1u)) >> 16);  // RNE
}

// wA[p*512 + lane*8 + j]: weight fragment, col=co=lane&15, k=(lane>>4)*8+j;
// mfma p covers taps {2p, 2p+1}; tap = 2p + (k>>4), ci = k&15.
__global__ __launch_bounds__(256) void conv_prep(const float* __restrict__ w,
                                                 unsigned short* __restrict__ wA) {
  int i = blockIdx.x * 256 + threadIdx.x;
  if (i >= 5 * 64 * 8) return;
  int j = i & 7;
  int l = (i >> 3) & 63;
  int p = i >> 9;
  int k = (l >> 4) * 8 + j;
  int t = 2 * p + (k >> 4);
  int ci = k & 15;
  int co = l & 15;
  float v = (t <= 8) ? w[co * 144 + ci * 9 + t] : 0.f;  // w[co][ci][ky][kx], t=ky*3+kx
  wA[i] = f2bf(v);
}

__global__ __launch_bounds__(256, 2) void conv_mfma(
    const float* __restrict__ x, const unsigned short* __restrict__ wA,
    float* __restrict__ out) {
  __shared__ __align__(16) char lds[LDS_BYTES];

  const int tid  = threadIdx.x;
  const int lane = tid & 63;
  const int wave = tid >> 6;
  const int m = lane & 15;   // A row = pixel within 16-px group
  const int q = lane >> 4;   // k-quarter
  const int colbase  = blockIdx.x * TW;
  const int rowbase0 = blockIdx.y * (TH * NT);

  // ---- staging geometry (tile-invariant): 10 rows x 18 float4-quads ----
  const bool stager = tid < 180;
  int ly = 0;
  const float* xcol = x;
  float cmask[4];
  int lok[4], lb[4];
  if (stager) {
    ly = tid / 18;                     // 0..9
    const int qx  = tid - ly * 18;     // 0..17
    const int gx0 = colbase - 4 + 4 * qx;
    const int gx0c = gx0 < 0 ? 0 : (gx0 > W - 4 ? W - 4 : gx0);
    xcol = x + gx0c;                   // column base, always valid & 16-B aligned
#pragma unroll
    for (int i = 0; i < 4; ++i) {
      const int gx = gx0 + i;
      cmask[i] = ((unsigned)gx < (unsigned)W) ? 1.f : 0.f;
      const int lx = gx - (colbase - 1);
      lok[i] = (unsigned)lx < 66u;
      const int b = ly * LPITCH + lx * 32;
      lb[i] = b ^ (((lx >> 2) & 3) << 4);   // swizzle folded in (b bits 0-4 are 0)
    }
  }

  // ---- double-buffered load registers + row masks ----
  f32x4 L[2][16];
  float rowm[2];

  // ---- prologue: issue tile 0 loads ----
  {
    const int gy = rowbase0 - 1 + ly;
    rowm[0] = ((unsigned)gy < (unsigned)H) ? 1.f : 0.f;
    const int gyc = gy < 0 ? 0 : (gy > H - 1 ? H - 1 : gy);
    const float* xb = xcol + gyc * W;
    if (stager) {
#pragma unroll
      for (int c = 0; c < 16; ++c)
        L[0][c] = *(const f32x4*)(xb + c * HW);
    }
  }

  // ---- weight fragments: 5 x 16B uniform cached loads ----
  ushort8 wU[5];
#pragma unroll
  for (int p = 0; p < 5; ++p)
    wU[p] = *(const ushort8*)&wA[(p * 64 + lane) * 8];

  // ---- per-lane LDS read base addresses (tile-invariant) ----
  int baseaddr[5];
#pragma unroll
  for (int p = 0; p < 5; ++p) {
    int t = 2 * p + (q >> 1);
    int ky = 0, kx = 0;
    if (t <= 8) { ky = t / 3; kx = t - ky * 3; }  // t==9: valid addr, zero weights
    int col = m + kx;
    int b = ky * LPITCH + col * 32 + (q & 1) * 16;
    b ^= ((col >> 2) & 3) << 4;
    baseaddr[p] = b + wave * 2 * LPITCH;
  }

#pragma unroll
  for (int t = 0; t < NT; ++t) {
    const int cur = t & 1, nxt = cur ^ 1;

    // ---- issue tile t+1 loads FIRST: in flight across pack+barrier+compute
    if (t + 1 < NT) {
      const int gy = rowbase0 + (t + 1) * TH - 1 + ly;
      rowm[nxt] = ((unsigned)gy < (unsigned)H) ? 1.f : 0.f;
      const int gyc = gy < 0 ? 0 : (gy > H - 1 ? H - 1 : gy);
      const float* xb = xcol + gyc * W;
      if (stager) {
#pragma unroll
        for (int c = 0; c < 16; ++c)
          L[nxt][c] = *(const f32x4*)(xb + c * HW);
      }
    }

    // ---- pack + LDS write tile t (compiler emits counted vmcnt here) ----
    if (stager) {
      char* const tb = lds + cur * LDS_TILE;
#pragma unroll
      for (int h = 0; h < 2; ++h) {
#pragma unroll
        for (int i = 0; i < 4; ++i) {
          if (lok[i]) {
            const float fm = rowm[cur] * cmask[i];
            uint4v d;
#pragma unroll
            for (int p = 0; p < 4; ++p) {
              const unsigned lo = f2bf(L[cur][h * 8 + 2 * p][i] * fm);
              const unsigned hi = f2bf(L[cur][h * 8 + 2 * p + 1][i] * fm);
              d[p] = lo | (hi << 16);
            }
            *(uint4v*)(tb + (lb[i] ^ (h << 4))) = d;
          }
        }
      }
    }

    // ---- raw barrier: ds_writes visible, global loads NOT drained ----
    asm volatile("s_waitcnt lgkmcnt(0)" ::: "memory");
    asm volatile("s_barrier" ::: "memory");

    // ---- compute tile t from buf[cur] ----
    const int rowbase = rowbase0 + t * TH;
    const char* const bufp = lds + cur * LDS_TILE;
#pragma unroll
    for (int r = 0; r < 2; ++r) {
#pragma unroll
      for (int g = 0; g < 4; ++g) {
        f32x4 acc = {0.f, 0.f, 0.f, 0.f};
#pragma unroll
        for (int p = 0; p < 5; ++p) {
          ushort8 bU = *(const ushort8*)(bufp + baseaddr[p] + r * LPITCH + g * 512);
          acc = __builtin_amdgcn_mfma_f32_16x16x32_bf16(
              __builtin_bit_cast(bf16x8, bU),       // A = pixels
              __builtin_bit_cast(bf16x8, wU[p]),    // B = weights
              acc, 0, 0, 0);
        }
        // D: col = lane&15 = c_out, row = q*4+j = pixel -> float4 store.
        const int y  = rowbase + wave * 2 + r;
        const int x0 = colbase + g * 16 + q * 4;
        *(f32x4*)(out + m * HW + y * W + x0) = acc;
      }
    }
    // No trailing barrier: pack(t+1) targets buf[nxt], whose last readers
    // (compute(t-1)) completed before this iteration's barrier.
  }
}

extern "C" void kernel_launch(void* const* d_in, const int* in_sizes, int n_in,
                              void* d_out, int out_size, void* d_ws, size_t ws_size,
                              hipStream_t stream) {
  const float* x = (const float*)d_in[0];            // (1,16,1024,1024) fp32
  const float* w = (const float*)d_in[1];            // (16,16,3,3) fp32
  float* out = (float*)d_out;                        // (16,1024,1024) fp32
  unsigned short* wA = (unsigned short*)d_ws;        // 2560 ushorts = 5120 B

  conv_prep<<<10, 256, 0, stream>>>(w, wA);

  dim3 grid(W / TW, H / (TH * NT));                  // 16 x 32 = 512 blocks
  conv_mfma<<<grid, 256, 0, stream>>>(x, wA, out);
}

// Round 4
// 39.492 us; speedup vs baseline: 1.1746x; 1.1746x over previous
//
#include <hip/hip_runtime.h>

// Conv2d 16->16, k=3, stride 1, pad 1, H=W=1024.
// Round 5: widen tile to TW=128 to double HBM run length.
//   Rounds 1-4 post-mortem: four different schedules all pinned at
//   3.0-3.7 TB/s -> not a scheduling problem; the TW=64 tile moves ALL
//   traffic as 256-288 B chunks strided 4 KB (16 channel-planes 4 MB
//   apart) = DRAM page-locality ceiling (~50% eff). fillBuffer (seq
//   stores) hits 6.5 TB/s on the same chip. Fix is geometric: TW=128
//   doubles per-channel contiguous runs to 512-544 B.
//   Structure reverts to the simple one-tile-per-block + __syncthreads
//   form (3 blocks/CU via 41.6 KB LDS; cross-block overlap hides phases).
//   GEMM view per tile unchanged: D[px][co] = sum_k B[px][k]*A[k][co],
//   K=160 = 5 x mfma_f32_16x16x32_bf16; LDS [y][x][ci] bf16 with 2-bit
//   XOR swizzle on byte bits 4-5; weights pre-shuffled by prep kernel.
//   Grid x-dim = 8 = #XCDs: each XCD owns one tile column -> vertical
//   halo rows shared through that XCD's L2.

#define H 1024
#define W 1024
#define HW (H * W)
#define TW 128
#define TH 8
#define LROWS 10             // TH + 2 halo rows
#define NQ 34                // float4-quads per halo row ([colbase-4, colbase+132))
#define NJOBS (LROWS * NQ)   // 340
#define LCOLS 130            // staged cols: lx in [0, 130)
#define LPITCH (LCOLS * 32)  // 4160 B (32 B per col = 16 ci * 2 B)
#define LDS_BYTES (LROWS * LPITCH)   // 41600

typedef __bf16 bf16x8 __attribute__((ext_vector_type(8)));
typedef float f32x4 __attribute__((ext_vector_type(4)));
typedef unsigned short ushort8 __attribute__((ext_vector_type(8)));
typedef unsigned int uint4v __attribute__((ext_vector_type(4)));

__device__ __host__ inline unsigned short f2bf(float f) {
  unsigned u = __builtin_bit_cast(unsigned, f);
  return (unsigned short)((u + 0x7fffu + ((u >> 16) & 1u)) >> 16);  // RNE
}

// wA[p*512 + lane*8 + j]: weight fragment, col=co=lane&15, k=(lane>>4)*8+j;
// mfma p covers taps {2p, 2p+1}; tap = 2p + (k>>4), ci = k&15.
__global__ __launch_bounds__(256) void conv_prep(const float* __restrict__ w,
                                                 unsigned short* __restrict__ wA) {
  int i = blockIdx.x * 256 + threadIdx.x;
  if (i >= 5 * 64 * 8) return;
  int j = i & 7;
  int l = (i >> 3) & 63;
  int p = i >> 9;
  int k = (l >> 4) * 8 + j;
  int t = 2 * p + (k >> 4);
  int ci = k & 15;
  int co = l & 15;
  float v = (t <= 8) ? w[co * 144 + ci * 9 + t] : 0.f;  // w[co][ci][ky][kx], t=ky*3+kx
  wA[i] = f2bf(v);
}

// One staging job: 4 cols x 16 channels. 16 x global_load_dwordx4 batched
// (max MLP), pack fp32->bf16 pairs, 8 x ds_write_b128.
__device__ __forceinline__ void stage_job(int j, const float* __restrict__ x,
                                          int colbase, int rowbase, char* lds) {
  const int ly  = j / NQ;            // 0..9
  const int qx  = j - ly * NQ;       // 0..33
  const int gy  = rowbase - 1 + ly;
  const float rowm = ((unsigned)gy < (unsigned)H) ? 1.f : 0.f;
  const int gyc  = gy < 0 ? 0 : (gy > H - 1 ? H - 1 : gy);
  const int gx0  = colbase - 4 + 4 * qx;
  const int gx0c = gx0 < 0 ? 0 : (gx0 > W - 4 ? W - 4 : gx0);
  const float* xb = x + gyc * W + gx0c;   // always valid, 16-B aligned

  f32x4 L[16];
#pragma unroll
  for (int c = 0; c < 16; ++c)
    L[c] = *(const f32x4*)(xb + c * HW);

#pragma unroll
  for (int i = 0; i < 4; ++i) {
    const int gx = gx0 + i;
    const int lx = gx - (colbase - 1);
    if ((unsigned)lx < (unsigned)LCOLS) {
      const float fm = rowm * (((unsigned)gx < (unsigned)W) ? 1.f : 0.f);
      const int lb = (ly * LPITCH + lx * 32) ^ (((lx >> 2) & 3) << 4);
#pragma unroll
      for (int h = 0; h < 2; ++h) {
        uint4v d;
#pragma unroll
        for (int p = 0; p < 4; ++p) {
          const unsigned lo = f2bf(L[h * 8 + 2 * p][i] * fm);
          const unsigned hi = f2bf(L[h * 8 + 2 * p + 1][i] * fm);
          d[p] = lo | (hi << 16);
        }
        *(uint4v*)(lds + (lb ^ (h << 4))) = d;
      }
    }
  }
}

__global__ __launch_bounds__(256, 3) void conv_mfma(
    const float* __restrict__ x, const unsigned short* __restrict__ wA,
    float* __restrict__ out) {
  __shared__ __align__(16) char lds[LDS_BYTES];

  const int tid  = threadIdx.x;
  const int lane = tid & 63;
  const int wave = tid >> 6;
  const int m = lane & 15;   // A row = pixel within 16-px group
  const int q = lane >> 4;   // k-quarter
  const int colbase = blockIdx.x * TW;
  const int rowbase = blockIdx.y * TH;

  // ---- stage: 340 jobs over 256 threads (second batch for tid<84) ----
  stage_job(tid, x, colbase, rowbase, lds);
  if (tid < NJOBS - 256) stage_job(256 + tid, x, colbase, rowbase, lds);

  // ---- weight fragments: 5 x 16B uniform cached loads ----
  ushort8 wU[5];
#pragma unroll
  for (int p = 0; p < 5; ++p)
    wU[p] = *(const ushort8*)&wA[(p * 64 + lane) * 8];

  // ---- per-lane LDS read base addresses ----
  int baseaddr[5];
#pragma unroll
  for (int p = 0; p < 5; ++p) {
    int t = 2 * p + (q >> 1);
    int ky = 0, kx = 0;
    if (t <= 8) { ky = t / 3; kx = t - ky * 3; }  // t==9: valid addr, zero weights
    int col = m + kx;
    int b = ky * LPITCH + col * 32 + (q & 1) * 16;
    b ^= ((col >> 2) & 3) << 4;
    baseaddr[p] = b + wave * 2 * LPITCH;
  }

  __syncthreads();

  // ---- compute: wave -> rows wave*2..+1, 8 groups of 16 px per row ----
#pragma unroll
  for (int r = 0; r < 2; ++r) {
#pragma unroll
    for (int g = 0; g < 8; ++g) {
      f32x4 acc = {0.f, 0.f, 0.f, 0.f};
#pragma unroll
      for (int p = 0; p < 5; ++p) {
        ushort8 bU = *(const ushort8*)(lds + (baseaddr[p] + r * LPITCH + g * 512));
        acc = __builtin_amdgcn_mfma_f32_16x16x32_bf16(
            __builtin_bit_cast(bf16x8, bU),       // A = pixels
            __builtin_bit_cast(bf16x8, wU[p]),    // B = weights
            acc, 0, 0, 0);
      }
      // D: col = lane&15 = c_out, row = q*4+j = pixel -> float4 store of 4
      // consecutive pixels for one channel.
      const int y  = rowbase + wave * 2 + r;
      const int x0 = colbase + g * 16 + q * 4;
      *(f32x4*)(out + m * HW + y * W + x0) = acc;
    }
  }
}

extern "C" void kernel_launch(void* const* d_in, const int* in_sizes, int n_in,
                              void* d_out, int out_size, void* d_ws, size_t ws_size,
                              hipStream_t stream) {
  const float* x = (const float*)d_in[0];            // (1,16,1024,1024) fp32
  const float* w = (const float*)d_in[1];            // (16,16,3,3) fp32
  float* out = (float*)d_out;                        // (16,1024,1024) fp32
  unsigned short* wA = (unsigned short*)d_ws;        // 2560 ushorts = 5120 B

  conv_prep<<<10, 256, 0, stream>>>(w, wA);

  dim3 grid(W / TW, H / TH);                         // 8 x 128 = 1024 blocks
  conv_mfma<<<grid, 256, 0, stream>>>(x, wA, out);
}